// Round 1
// baseline (5660.232 us; speedup 1.0000x reference)
//
#include <hip/hip_runtime.h>
#include <hip/hip_bf16.h>

typedef __hip_bfloat16 bf16;

#define BB 2
#define CCH 128
#define HHH 256
#define WWW 510
#define WFQ 256
#define HWP 130560                  // HHH*WWW
#define NROW 65536                  // BB*CCH*HHH
#define UPL 16777216L               // NROW*WFQ  (one re or im plane, elements)

__device__ __forceinline__ float b2f(bf16 v){ return __bfloat162float(v); }
__device__ __forceinline__ bf16  f2b(float v){ return __float2bfloat16(v); }
__device__ __forceinline__ float ldin(const void* p, long i, int f32){
  return f32 ? ((const float*)p)[i] : b2f(((const bf16*)p)[i]);
}
__device__ __forceinline__ float sigm(float z){ return 1.f/(1.f+__expf(-z)); }

// ---------------------------------------------------------------- detect dtype
// If inputs are f32, interpreting element pairs as bf16 makes the EVEN slots the
// low mantissa halves -> log-uniform garbage exponents. If inputs are bf16 the
// even slots are just normal N(0,1) samples. flag=1 => inputs are f32.
__global__ void k_detect(const void* __restrict__ g, int* __restrict__ flag){
  __shared__ int cnt[256];
  int t = threadIdx.x;
  const bf16* pb = (const bf16*)g;
  int c = 0;
  for(int i=0;i<16;i++){
    int idx = t*16 + i;
    float v = b2f(pb[2*idx]);
    unsigned bits = __float_as_uint(v);
    int ex = (bits>>23)&0xff;
    if(ex >= 117 && ex <= 137) c++;   // |v| in [2^-10, 2^10], finite
  }
  cnt[t]=c; __syncthreads();
  for(int s=128;s>0;s>>=1){ if(t<s) cnt[t]+=cnt[t+s]; __syncthreads(); }
  if(t==0) *flag = (cnt[0] < 2048) ? 1 : 0;
}

// ---------------------------------------------------------------- DFT tables
__global__ void k_tables(float* __restrict__ trc, float* __restrict__ trs,
                         float* __restrict__ tfc, float* __restrict__ tfs,
                         float* __restrict__ tic, float* __restrict__ tis){
  int idx = blockIdx.x*256 + threadIdx.x;      // 0 .. 130559
  const float s510 = rsqrtf(510.0f);
  const float TP = 6.283185307179586f;
  {
    // forward rfft along W, [w][k]
    int w = idx >> 8, k = idx & 255;
    int r = (w*k) % 510;
    float ang = (TP/510.0f) * (float)r;
    trc[idx] =  cosf(ang) * s510;
    trs[idx] = -sinf(ang) * s510;
  }
  {
    // inverse rfft along W, [k][w], with hermitian-fold coeff c_k
    int k = idx / 510, w = idx % 510;
    int r = (k*w) % 510;
    float ang = (TP/510.0f) * (float)r;
    float ck = (k==0 || k==255) ? 1.0f : 2.0f;
    tic[idx] =  ck * cosf(ang) * s510;
    tis[idx] = -ck * sinf(ang) * s510;
  }
  if(idx < 65536){
    // symmetric H-FFT twiddles [a][b], scale 1/sqrt(256)
    int a = idx >> 8, b = idx & 255;
    int r = (a*b) & 255;
    float ang = (TP/256.0f) * (float)r;
    tfc[idx] = cosf(ang) * 0.0625f;
    tfs[idx] = sinf(ang) * 0.0625f;
  }
}

// ---------------------------------------------------------------- 1x1 conv
// out[b,o,hw] = sum_c w[o,c]*in[b,c,hw] + bias[o]
// block: 256 thr, tile = 256 hw x 32 o; grid (510, 4, 2)
__global__ __launch_bounds__(256) void k_conv(const void* __restrict__ in,
    const void* __restrict__ wmat, const void* __restrict__ bias,
    const int* __restrict__ flagp, bf16* __restrict__ out){
  __shared__ bf16  wlb[32][128];
  __shared__ float xl[8][256];
  int f32 = *flagp;
  int t = threadIdx.x, tx = t&63, ty = t>>6;
  int hw0 = blockIdx.x*256, oy = blockIdx.y, b = blockIdx.z;
  #pragma unroll
  for(int i=0;i<16;i++){ int e=t+256*i; int ol=e>>7, c=e&127;
    wlb[ol][c] = f2b(ldin(wmat, (long)(oy*32+ol)*128 + c, f32)); }
  float acc[8][4];
  #pragma unroll
  for(int j=0;j<8;j++) for(int hh=0;hh<4;hh++) acc[j][hh]=0.f;
  long inb = (long)b*CCH*HWP;
  for(int c0=0;c0<128;c0+=8){
    __syncthreads();
    #pragma unroll
    for(int i=0;i<8;i++){ int e=t+256*i; int cc=e>>8, pp=e&255;
      xl[cc][pp] = ldin(in, inb + (long)(c0+cc)*HWP + hw0+pp, f32); }
    __syncthreads();
    float xq[8][4];
    #pragma unroll
    for(int cc=0;cc<8;cc++)
      #pragma unroll
      for(int hh=0;hh<4;hh++) xq[cc][hh] = xl[cc][tx+64*hh];
    #pragma unroll
    for(int j=0;j<8;j++){
      int ol = ty+4*j;
      uint4 wq = *(const uint4*)&wlb[ol][c0];
      float wv[8];
      wv[0]=__uint_as_float(wq.x<<16); wv[1]=__uint_as_float(wq.x&0xffff0000u);
      wv[2]=__uint_as_float(wq.y<<16); wv[3]=__uint_as_float(wq.y&0xffff0000u);
      wv[4]=__uint_as_float(wq.z<<16); wv[5]=__uint_as_float(wq.z&0xffff0000u);
      wv[6]=__uint_as_float(wq.w<<16); wv[7]=__uint_as_float(wq.w&0xffff0000u);
      #pragma unroll
      for(int cc=0;cc<8;cc++)
        #pragma unroll
        for(int hh=0;hh<4;hh++) acc[j][hh] = fmaf(wv[cc], xq[cc][hh], acc[j][hh]);
    }
  }
  #pragma unroll
  for(int j=0;j<8;j++){
    int o = oy*32 + ty+4*j;
    float bv = ldin(bias, o, f32);
    #pragma unroll
    for(int hh=0;hh<4;hh++)
      out[inb + (long)o*HWP + hw0 + tx+64*hh] = f2b(acc[j][hh] + bv);
  }
}

// ---------------------------------------------------------------- rfft along W
// Gr/Gi[row,k] = sum_w Y[row,w] * (trc/trs)[w,k] ; rows = 65536, tile 32x128
__global__ __launch_bounds__(256) void k_rfft(const bf16* __restrict__ Y,
    const float* __restrict__ tc, const float* __restrict__ ts,
    bf16* __restrict__ Gr, bf16* __restrict__ Gi){
  __shared__ float yl[32][36];
  __shared__ float cl[32][128];
  __shared__ float sl[32][128];
  int t=threadIdx.x, tx=t&63, ty=t>>6;
  int m0 = blockIdx.x*32, n0 = blockIdx.y*128;
  float ar[8][2], ai[8][2];
  #pragma unroll
  for(int i=0;i<8;i++){ ar[i][0]=ar[i][1]=ai[i][0]=ai[i][1]=0.f; }
  for(int k0=0;k0<512;k0+=32){
    __syncthreads();
    #pragma unroll
    for(int i=0;i<4;i++){ int e=t+256*i; int m=e>>5, kk=e&31; int w=k0+kk;
      yl[m][kk] = (w<510) ? b2f(Y[(long)(m0+m)*510 + w]) : 0.f; }
    #pragma unroll
    for(int i=0;i<16;i++){ int e=t+256*i; int kk=e>>7, n=e&127; int w=k0+kk;
      cl[kk][n] = (w<510) ? tc[w*256 + n0+n] : 0.f;
      sl[kk][n] = (w<510) ? ts[w*256 + n0+n] : 0.f; }
    __syncthreads();
    #pragma unroll
    for(int kk0=0;kk0<32;kk0+=4){
      float cv[4][2], sv[4][2];
      #pragma unroll
      for(int q=0;q<4;q++){
        cv[q][0]=cl[kk0+q][tx]; cv[q][1]=cl[kk0+q][tx+64];
        sv[q][0]=sl[kk0+q][tx]; sv[q][1]=sl[kk0+q][tx+64]; }
      #pragma unroll
      for(int mm=0;mm<8;mm++){
        float4 y4 = *(const float4*)&yl[ty+4*mm][kk0];
        const float* yp = (const float*)&y4;
        #pragma unroll
        for(int q=0;q<4;q++){
          #pragma unroll
          for(int nn=0;nn<2;nn++){
            ar[mm][nn] = fmaf(yp[q], cv[q][nn], ar[mm][nn]);
            ai[mm][nn] = fmaf(yp[q], sv[q][nn], ai[mm][nn]);
          }
        }
      }
    }
  }
  #pragma unroll
  for(int mm=0;mm<8;mm++){
    long row = m0 + ty + 4*mm;
    #pragma unroll
    for(int nn=0;nn<2;nn++){
      int n = n0 + tx + 64*nn;
      Gr[row*256 + n] = f2b(ar[mm][nn]);
      Gi[row*256 + n] = f2b(ai[mm][nn]);
    }
  }
}

// ---------------------------------------------------------------- FFT/iFFT along H (+ optional filter)
// Out[m,n] = sum_h (tc[m,h] + i*sgn*ts[m,h]) * (Ar+ i Ai)[h,n], per bc plane.
// fwd: sgn=+1 internally folded => accr = c*ar + s'*ai, acci = c*ai - s'*ar (s' = sgn-folded)
__global__ __launch_bounds__(256) void k_ffth(const bf16* __restrict__ Ar, const bf16* __restrict__ Ai,
    const float* __restrict__ tc, const float* __restrict__ ts, float sgn,
    const void* __restrict__ filt, const int* __restrict__ flagp,
    bf16* __restrict__ Or_, bf16* __restrict__ Oi_){
  __shared__ float ctl[32][36], stl[32][36];
  __shared__ float grl[32][128], gil[32][128];
  int f32 = *flagp;
  int t=threadIdx.x, tx=t&63, ty=t>>6;
  int m0=blockIdx.x*32, n0=blockIdx.y*128, bc=blockIdx.z;
  long base = (long)bc*65536;
  float accr[8][2], acci[8][2];
  #pragma unroll
  for(int i=0;i<8;i++){ accr[i][0]=accr[i][1]=acci[i][0]=acci[i][1]=0.f; }
  for(int k0=0;k0<256;k0+=32){
    __syncthreads();
    #pragma unroll
    for(int i=0;i<4;i++){ int e=t+256*i; int m=e>>5, kk=e&31;
      ctl[m][kk] = tc[(m0+m)*256 + k0+kk];
      stl[m][kk] = sgn*ts[(m0+m)*256 + k0+kk]; }
    #pragma unroll
    for(int i=0;i<16;i++){ int e=t+256*i; int kk=e>>7, n=e&127;
      grl[kk][n] = b2f(Ar[base + (long)(k0+kk)*256 + n0+n]);
      gil[kk][n] = b2f(Ai[base + (long)(k0+kk)*256 + n0+n]); }
    __syncthreads();
    #pragma unroll
    for(int kk0=0;kk0<32;kk0+=4){
      float grv[4][2], giv[4][2];
      #pragma unroll
      for(int q=0;q<4;q++){
        grv[q][0]=grl[kk0+q][tx]; grv[q][1]=grl[kk0+q][tx+64];
        giv[q][0]=gil[kk0+q][tx]; giv[q][1]=gil[kk0+q][tx+64]; }
      #pragma unroll
      for(int mm=0;mm<8;mm++){
        int m = ty+4*mm;
        float4 c4 = *(const float4*)&ctl[m][kk0];
        float4 s4 = *(const float4*)&stl[m][kk0];
        const float* cp=(const float*)&c4; const float* sp=(const float*)&s4;
        #pragma unroll
        for(int q=0;q<4;q++){
          #pragma unroll
          for(int nn=0;nn<2;nn++){
            accr[mm][nn] = fmaf(cp[q], grv[q][nn], accr[mm][nn]);
            accr[mm][nn] = fmaf(sp[q], giv[q][nn], accr[mm][nn]);
            acci[mm][nn] = fmaf(cp[q], giv[q][nn], acci[mm][nn]);
            acci[mm][nn] = fmaf(-sp[q], grv[q][nn], acci[mm][nn]);
          }
        }
      }
    }
  }
  int c_ch = bc & (CCH-1);
  #pragma unroll
  for(int mm=0;mm<8;mm++){
    int m = m0 + ty + 4*mm;
    #pragma unroll
    for(int nn=0;nn<2;nn++){
      int n = n0 + tx + 64*nn;
      float r = accr[mm][nn], im = acci[mm][nn];
      float orr = r, oii = im;
      if(filt){
        long fi = (((long)c_ch*256 + m)*256 + n)*2;
        float wr = ldin(filt, fi, f32), wi = ldin(filt, fi+1, f32);
        orr = r*wr - im*wi; oii = r*wi + im*wr;
      }
      Or_[base + (long)m*256 + n] = f2b(orr);
      Oi_[base + (long)m*256 + n] = f2b(oii);
    }
  }
}

// ---------------------------------------------------------------- row variance -> 1/sqrt(2*pi*var)
__global__ __launch_bounds__(256) void k_var(const bf16* __restrict__ Gr,
    const bf16* __restrict__ Gi, float* __restrict__ rinv){
  int row = blockIdx.x*4 + (threadIdx.x>>6);
  int lane = threadIdx.x & 63;
  long base = (long)row*256;
  float sr=0.f, si=0.f, s2=0.f;
  #pragma unroll
  for(int i=0;i<4;i++){
    int k = lane + 64*i;
    float r = b2f(Gr[base+k]), im = b2f(Gi[base+k]);
    sr += r; si += im; s2 += r*r + im*im;
  }
  #pragma unroll
  for(int off=32;off>0;off>>=1){
    sr += __shfl_down(sr,off); si += __shfl_down(si,off); s2 += __shfl_down(s2,off);
  }
  if(lane==0){
    float mr = sr*(1.f/256.f), mi = si*(1.f/256.f);
    float v = s2*(1.f/256.f) - mr*mr - mi*mi;
    v = fmaxf(v, 1e-20f);
    rinv[row] = rsqrtf(6.283185307179586f * v);
  }
}

// ---------------------------------------------------------------- scores = g2^T x2, scale, sigmoid
__global__ __launch_bounds__(256) void k_scores(const bf16* __restrict__ Gr, const bf16* __restrict__ Gi,
    const bf16* __restrict__ Xr, const bf16* __restrict__ Xi,
    const float* __restrict__ rinv, bf16* __restrict__ Sr, bf16* __restrict__ Si){
  __shared__ float arl[32][40], ail[32][40];
  __shared__ float brl[32][128], bil[32][128];
  int t=threadIdx.x, tx=t&63, ty=t>>6;
  int m0=blockIdx.x*32, n0=blockIdx.y*128, bc=blockIdx.z;
  long base=(long)bc*65536;
  float accr[8][2], acci[8][2];
  #pragma unroll
  for(int i=0;i<8;i++){ accr[i][0]=accr[i][1]=acci[i][0]=acci[i][1]=0.f; }
  for(int k0=0;k0<256;k0+=32){
    __syncthreads();
    #pragma unroll
    for(int i=0;i<4;i++){ int e=t+256*i; int kk=e>>5, j=e&31;
      arl[j][kk] = b2f(Gr[base + (long)(k0+kk)*256 + m0+j]);
      ail[j][kk] = b2f(Gi[base + (long)(k0+kk)*256 + m0+j]); }
    #pragma unroll
    for(int i=0;i<16;i++){ int e=t+256*i; int kk=e>>7, n=e&127;
      brl[kk][n] = b2f(Xr[base + (long)(k0+kk)*256 + n0+n]);
      bil[kk][n] = b2f(Xi[base + (long)(k0+kk)*256 + n0+n]); }
    __syncthreads();
    #pragma unroll
    for(int kk0=0;kk0<32;kk0+=4){
      float brv[4][2], biv[4][2];
      #pragma unroll
      for(int q=0;q<4;q++){
        brv[q][0]=brl[kk0+q][tx]; brv[q][1]=brl[kk0+q][tx+64];
        biv[q][0]=bil[kk0+q][tx]; biv[q][1]=bil[kk0+q][tx+64]; }
      #pragma unroll
      for(int mm=0;mm<8;mm++){
        int m = ty+4*mm;
        float4 a4r = *(const float4*)&arl[m][kk0];
        float4 a4i = *(const float4*)&ail[m][kk0];
        const float* apr=(const float*)&a4r; const float* api=(const float*)&a4i;
        #pragma unroll
        for(int q=0;q<4;q++){
          #pragma unroll
          for(int nn=0;nn<2;nn++){
            accr[mm][nn] = fmaf(apr[q], brv[q][nn], accr[mm][nn]);
            accr[mm][nn] = fmaf(-api[q], biv[q][nn], accr[mm][nn]);
            acci[mm][nn] = fmaf(apr[q], biv[q][nn], acci[mm][nn]);
            acci[mm][nn] = fmaf(api[q], brv[q][nn], acci[mm][nn]);
          }
        }
      }
    }
  }
  #pragma unroll
  for(int mm=0;mm<8;mm++){
    int m = m0 + ty + 4*mm;
    float rv = rinv[bc*256 + m];
    #pragma unroll
    for(int nn=0;nn<2;nn++){
      int n = n0 + tx + 64*nn;
      Sr[base + (long)m*256 + n] = f2b(sigm(accr[mm][nn]*rv));
      Si[base + (long)m*256 + n] = f2b(sigm(acci[mm][nn]*rv));
    }
  }
}

// ---------------------------------------------------------------- irfft along W  (+ add x)
__global__ __launch_bounds__(256) void k_irfft(const bf16* __restrict__ Tr, const bf16* __restrict__ Ti,
    const float* __restrict__ mc, const float* __restrict__ ms,
    const void* __restrict__ xin, const int* __restrict__ flagp, float* __restrict__ R){
  __shared__ float trl[32][36], til[32][36];
  __shared__ float mcl[32][128], msl[32][128];
  int f32 = *flagp;
  int t=threadIdx.x, tx=t&63, ty=t>>6;
  int m0=blockIdx.x*32, n0=blockIdx.y*128;
  float acc[8][2];
  #pragma unroll
  for(int i=0;i<8;i++){ acc[i][0]=acc[i][1]=0.f; }
  for(int k0=0;k0<256;k0+=32){
    __syncthreads();
    #pragma unroll
    for(int i=0;i<4;i++){ int e=t+256*i; int m=e>>5, kk=e&31;
      trl[m][kk] = b2f(Tr[(long)(m0+m)*256 + k0+kk]);
      til[m][kk] = b2f(Ti[(long)(m0+m)*256 + k0+kk]); }
    #pragma unroll
    for(int i=0;i<16;i++){ int e=t+256*i; int kk=e>>7, n=e&127; int w=n0+n;
      mcl[kk][n] = (w<510) ? mc[(long)(k0+kk)*510 + w] : 0.f;
      msl[kk][n] = (w<510) ? ms[(long)(k0+kk)*510 + w] : 0.f; }
    __syncthreads();
    #pragma unroll
    for(int kk0=0;kk0<32;kk0+=4){
      float cv[4][2], sv[4][2];
      #pragma unroll
      for(int q=0;q<4;q++){
        cv[q][0]=mcl[kk0+q][tx]; cv[q][1]=mcl[kk0+q][tx+64];
        sv[q][0]=msl[kk0+q][tx]; sv[q][1]=msl[kk0+q][tx+64]; }
      #pragma unroll
      for(int mm=0;mm<8;mm++){
        int m = ty+4*mm;
        float4 t4r = *(const float4*)&trl[m][kk0];
        float4 t4i = *(const float4*)&til[m][kk0];
        const float* tpr=(const float*)&t4r; const float* tpi=(const float*)&t4i;
        #pragma unroll
        for(int q=0;q<4;q++){
          #pragma unroll
          for(int nn=0;nn<2;nn++){
            acc[mm][nn] = fmaf(tpr[q], cv[q][nn], acc[mm][nn]);
            acc[mm][nn] = fmaf(tpi[q], sv[q][nn], acc[mm][nn]);
          }
        }
      }
    }
  }
  #pragma unroll
  for(int mm=0;mm<8;mm++){
    long row = m0 + ty + 4*mm;
    #pragma unroll
    for(int nn=0;nn<2;nn++){
      int w = n0 + tx + 64*nn;
      if(w < 510){
        float v = acc[mm][nn] + ldin(xin, row*510 + w, f32);
        R[row*510 + w] = v;
      }
    }
  }
}

// ---------------------------------------------------------------- channel LayerNorm
__global__ __launch_bounds__(256) void k_ln(const float* __restrict__ R,
    const void* __restrict__ gamma, const void* __restrict__ beta,
    const int* __restrict__ flagp, void* __restrict__ out){
  int f32 = *flagp;
  int p = blockIdx.x*256 + threadIdx.x;       // 0 .. B*HW-1
  int b = p / HWP, hw = p % HWP;
  long base = (long)b*CCH*HWP + hw;
  float sum=0.f, sq=0.f;
  for(int c=0;c<CCH;c++){
    float v = R[base + (long)c*HWP];
    sum += v; sq += v*v;
  }
  float mu = sum*(1.f/128.f);
  float var = sq*(1.f/128.f) - mu*mu;
  float inv = rsqrtf(fmaxf(var,0.f) + 1e-6f);
  for(int c=0;c<CCH;c++){
    float v = (R[base + (long)c*HWP] - mu)*inv;
    float o = ldin(gamma,c,f32)*v + ldin(beta,c,f32);
    long oi = base + (long)c*HWP;
    if(f32) ((float*)out)[oi] = o;
    else    ((bf16*)out)[oi]  = f2b(o);
  }
}

// ================================================================ launcher
extern "C" void kernel_launch(void* const* d_in, const int* in_sizes, int n_in,
                              void* d_out, int out_size, void* d_ws, size_t ws_size,
                              hipStream_t stream) {
  const void* g   = d_in[0];
  const void* x   = d_in[1];
  const void* wg  = d_in[2];
  const void* bg  = d_in[3];
  const void* wx  = d_in[4];
  const void* bx  = d_in[5];
  const void* fg  = d_in[6];
  const void* fx  = d_in[7];
  const void* gam = d_in[8];
  const void* bet = d_in[9];

  // workspace carve (needs ~204.2 MB)
  bf16* A  = (bf16*)d_ws;          // 2*UPL elems
  bf16* Bq = A + 2*UPL;            // 2*UPL elems
  bf16* Cq = A + 4*UPL;            // 2*UPL elems
  char* pp = (char*)d_ws + 12L*UPL;
  float* rinv = (float*)pp; pp += 65536L*4;
  float* trc  = (float*)pp; pp += 130560L*4;
  float* trs  = (float*)pp; pp += 130560L*4;
  float* tfc  = (float*)pp; pp += 65536L*4;
  float* tfs  = (float*)pp; pp += 65536L*4;
  float* tic  = (float*)pp; pp += 130560L*4;
  float* tis  = (float*)pp; pp += 130560L*4;
  int* flag   = (int*)pp;
  float* R    = (float*)A;         // overlays regions A+B (both dead by then)

  k_detect<<<1,256,0,stream>>>(g, flag);
  k_tables<<<510,256,0,stream>>>(trc,trs,tfc,tfs,tic,tis);

  // --- g path: conv -> rfft_W -> FFT_H*filter  => G2 in C
  k_conv <<<dim3(510,4,2),256,0,stream>>>(g, wg, bg, flag, A);
  k_rfft <<<dim3(2048,2),256,0,stream>>>(A, trc, trs, Bq, Bq+UPL);
  k_ffth <<<dim3(8,2,256),256,0,stream>>>(Bq, Bq+UPL, tfc, tfs, +1.f, fg, flag, Cq, Cq+UPL);

  // --- x path: conv -> rfft_W -> FFT_H*filter  => X2 in A
  k_conv <<<dim3(510,4,2),256,0,stream>>>(x, wx, bx, flag, A);
  k_rfft <<<dim3(2048,2),256,0,stream>>>(A, trc, trs, Bq, Bq+UPL);
  k_ffth <<<dim3(8,2,256),256,0,stream>>>(Bq, Bq+UPL, tfc, tfs, +1.f, fx, flag, A, A+UPL);

  // --- variance of G2 rows -> rinv
  k_var  <<<16384,256,0,stream>>>(Cq, Cq+UPL, rinv);

  // --- scores + sigmoid => atten in B
  k_scores<<<dim3(8,2,256),256,0,stream>>>(Cq, Cq+UPL, A, A+UPL, rinv, Bq, Bq+UPL);

  // --- inverse FFT along H => T in C
  k_ffth <<<dim3(8,2,256),256,0,stream>>>(Bq, Bq+UPL, tfc, tfs, -1.f, nullptr, flag, Cq, Cq+UPL);

  // --- inverse rfft along W, + x  => R (f32) over A+B
  k_irfft<<<dim3(2048,4),256,0,stream>>>(Cq, Cq+UPL, tic, tis, x, flag, R);

  // --- channel LayerNorm => out
  k_ln   <<<1020,256,0,stream>>>(R, gam, bet, flag, d_out);
}